// Round 8
// baseline (157.944 us; speedup 1.0000x reference)
//
#include <hip/hip_runtime.h>
#include <hip/hip_bf16.h>

#define BB 16
#define CC 512
#define LL 2048

typedef float f32x4 __attribute__((ext_vector_type(4)));
typedef short s16x8 __attribute__((ext_vector_type(8)));

static __device__ __forceinline__ float bf2f(unsigned short u) {
    union { unsigned int i; float f; } v; v.i = ((unsigned int)u) << 16; return v.f;
}
static __device__ __forceinline__ unsigned short f2bf(float f) {
    union { float fv; unsigned int i; } v; v.fv = f;
    unsigned int x = v.i;
    return (unsigned short)((x + 0x7FFFu + ((x >> 16) & 1u)) >> 16);  // RNE
}

// ---------------- K0: cast gate_w f32 -> bf16 [512][512] ----------------
__global__ void k0_cast(const float* __restrict__ gw, unsigned short* __restrict__ gwb) {
    int i = blockIdx.x * 256 + threadIdx.x;
    if (i < CC * CC) gwb[i] = f2bf(gw[i]);
}

// ------- K1: RMS over C per (b,l); write x_norm^T bf16 [B][L][C] + adx = sum_c x*lw -------
#define K1_ST 520   // ushort stride (1040 B, 16B-aligned)
__global__ __launch_bounds__(256) void k1_rms_t(
    const float* __restrict__ x, const float* __restrict__ pre_w,
    const float* __restrict__ lw,
    unsigned short* __restrict__ xnt, float* __restrict__ adx) {
    __shared__ unsigned short tile[32 * K1_ST];   // [l][c] bf16, 33.3 KB
    __shared__ float red[32 * 33];
    __shared__ float red2[32 * 33];
    __shared__ float pwS[CC];
    __shared__ float lwS[CC];
    __shared__ float ivS[32];
    const int tid = threadIdx.x;
    const int b  = blockIdx.x >> 6;      // 64 l-tiles of 32
    const int lt = blockIdx.x & 63;
    const int l0 = lt * 32;
    const float* xb = x + (size_t)(b * CC) * LL + l0;

    for (int i = tid; i < CC; i += 256) { pwS[i] = pre_w[i]; lwS[i] = lw[i]; }
    __syncthreads();

    const int lq = tid & 7;      // l-quad: l = lq*4..+3
    const int cr = tid >> 3;     // 0..31
    f32x4 ssq = {0.f, 0.f, 0.f, 0.f};
    f32x4 sdx = {0.f, 0.f, 0.f, 0.f};
    #pragma unroll
    for (int p = 0; p < 16; ++p) {
        int c = p * 32 + cr;
        float lwc = lwS[c];
        f32x4 v = *(const f32x4*)(xb + (size_t)c * LL + lq * 4);
        #pragma unroll
        for (int r = 0; r < 4; ++r) {
            ssq[r] += v[r] * v[r];
            sdx[r] += v[r] * lwc;
            tile[(lq * 4 + r) * K1_ST + c] = f2bf(v[r]);
        }
    }
    #pragma unroll
    for (int r = 0; r < 4; ++r) {
        red[(lq * 4 + r) * 33 + cr]  = ssq[r];
        red2[(lq * 4 + r) * 33 + cr] = sdx[r];
    }
    __syncthreads();
    if (tid < 32) {
        float s = 0.f, sa = 0.f;
        #pragma unroll
        for (int g = 0; g < 32; ++g) { s += red[tid * 33 + g]; sa += red2[tid * 33 + g]; }
        ivS[tid] = rsqrtf(s * (1.0f / CC) + 1e-5f);
        adx[b * LL + l0 + tid] = sa;
    }
    __syncthreads();
    unsigned short* xo = xnt + ((size_t)b * LL + l0) * CC;
    #pragma unroll
    for (int p = 0; p < 8; ++p) {
        int g = p * 256 + tid;          // 2048 granules of 8 ushorts
        int l = g >> 6, c8 = (g & 63) * 8;
        s16x8 t = *(const s16x8*)&tile[l * K1_ST + c8];
        f32x4 w0 = *(const f32x4*)&pwS[c8];
        f32x4 w1 = *(const f32x4*)&pwS[c8 + 4];
        float iv = ivS[l];
        s16x8 o;
        #pragma unroll
        for (int r = 0; r < 4; ++r) {
            o[r]     = (short)f2bf(bf2f((unsigned short)t[r])     * iv * w0[r]);
            o[r + 4] = (short)f2bf(bf2f((unsigned short)t[r + 4]) * iv * w1[r]);
        }
        *(s16x8*)(xo + (size_t)l * CC + c8) = o;
    }
}

// ------- K2_fused: GEMM (R6 core) + SiLU + conv*gate + post-RMS partials -------
// Grid (nt=8, mt=2, b=16). Block: 256 d-chunk x 256 l-chunk, 8 waves 2Mx4N.
// GEMM: BK=32, 3-buf LDS, counted vmcnt(8) (R6 verbatim). Then fused epilogue:
// per l-half of 128: stage xn[l-4..l+131][c-chunk] -> conv q (by c8 producers)
// -> qS bf16 (XOR-swizzled 8B granules) -> consumers multiply with silu'd gate
// (bf16 packed regs) -> per-chunk partial sums (sum p^2, sum p*pw*lw) -> part.
__global__ __launch_bounds__(512, 2) void k2_fused(
    const unsigned short* __restrict__ gwb,   // A [512][512] (d,c) row-major
    const unsigned short* __restrict__ xnt,   // B^T [B][2048][512] (l,c)
    const float* __restrict__ gate_b,
    const float* __restrict__ cw0, const float* __restrict__ cb0,
    const float* __restrict__ cw1, const float* __restrict__ cb1,
    const float* __restrict__ cw2, const float* __restrict__ cb2,
    const float* __restrict__ post_w, const float* __restrict__ lw,
    float* __restrict__ part) {
    union Sm {
        struct { unsigned short A[3][256 * 32], B[3][256 * 32]; } g;     // 96 KB
        struct {
            unsigned short xnS[136 * 256];   // 68 KB, linear [row][c]
            unsigned short qS[128 * 256];    // 64 KB, granule-XOR swizzled
            float redS[128 * 8 * 2];         // 8 KB
        } e;                                                              // 140 KB
    };
    __shared__ Sm sm;
    const int tid = threadIdx.x;
    const int w = tid >> 6, lane = tid & 63;
    const int lo = lane & 15, hi = lane >> 4;
    const int wm = w >> 2, wn = w & 3;           // 2M x 4N waves
    const int nt = blockIdx.x, mt = blockIdx.y, b = blockIdx.z;
    const int m0 = mt * 256, n0 = nt * 256;
    const unsigned short* Ab = gwb;
    const unsigned short* Bb = xnt + (size_t)b * LL * CC;

    // ---------------- GEMM (R6 core, verbatim) ----------------
    #define STG(kt_, buf_)                                                            \
        {                                                                             \
            _Pragma("unroll")                                                         \
            for (int s_ = 0; s_ < 2; ++s_) {                                          \
                int g_ = tid + s_ * 512;                                              \
                int row_ = g_ >> 2, gin_ = g_ & 3;                                    \
                int ks_ = (kt_) * 32 + ((gin_ ^ ((row_ >> 1) & 3)) * 8);              \
                __builtin_amdgcn_global_load_lds(                                     \
                    (const __attribute__((address_space(1))) void*)(Ab + (size_t)(m0 + row_) * CC + ks_), \
                    (__attribute__((address_space(3))) void*)(&sm.g.A[buf_][g_ * 8]), \
                    16, 0, 0);                                                        \
                __builtin_amdgcn_global_load_lds(                                     \
                    (const __attribute__((address_space(1))) void*)(Bb + (size_t)(n0 + row_) * CC + ks_), \
                    (__attribute__((address_space(3))) void*)(&sm.g.B[buf_][g_ * 8]), \
                    16, 0, 0);                                                        \
            }                                                                         \
        }

    f32x4 acc[8][4] = {};
    const int fsw = (lo >> 1) & 3;

    STG(0, 0);
    STG(1, 1);
    #pragma unroll
    for (int kt = 0; kt < 16; ++kt) {
        const int buf = kt % 3;
        if (kt < 14) {
            STG(kt + 2, (kt + 2) % 3);
            asm volatile("s_waitcnt vmcnt(8)" ::: "memory");
        } else if (kt == 14) {
            asm volatile("s_waitcnt vmcnt(4)" ::: "memory");
        } else {
            asm volatile("s_waitcnt vmcnt(0)" ::: "memory");
        }
        __builtin_amdgcn_s_barrier();
        s16x8 af[8], bfr[4];
        #pragma unroll
        for (int mi = 0; mi < 8; ++mi)
            af[mi] = *(const s16x8*)&sm.g.A[buf][(wm * 128 + mi * 16 + lo) * 32 + ((hi ^ fsw) * 8)];
        #pragma unroll
        for (int ni = 0; ni < 4; ++ni)
            bfr[ni] = *(const s16x8*)&sm.g.B[buf][(wn * 64 + ni * 16 + lo) * 32 + ((hi ^ fsw) * 8)];
        __builtin_amdgcn_s_setprio(1);
        #pragma unroll
        for (int mi = 0; mi < 8; ++mi)
            #pragma unroll
            for (int ni = 0; ni < 4; ++ni)
                acc[mi][ni] = __builtin_amdgcn_mfma_f32_16x16x32_bf16(
                    af[mi], bfr[ni], acc[mi][ni], 0, 0, 0);
        __builtin_amdgcn_s_setprio(0);
        asm volatile("" ::: "memory");
        __builtin_amdgcn_s_barrier();
    }
    #undef STG

    // ---- bias + SiLU -> bf16 packed gate (frees acc) ----
    unsigned int gpk[8][4][2];
    #pragma unroll
    for (int mi = 0; mi < 8; ++mi) {
        f32x4 gb4 = *(const f32x4*)(gate_b + m0 + wm * 128 + mi * 16 + hi * 4);
        #pragma unroll
        for (int ni = 0; ni < 4; ++ni) {
            f32x4 z = acc[mi][ni] + gb4;
            float s0 = z[0] / (1.0f + __expf(-z[0]));
            float s1 = z[1] / (1.0f + __expf(-z[1]));
            float s2 = z[2] / (1.0f + __expf(-z[2]));
            float s3 = z[3] / (1.0f + __expf(-z[3]));
            gpk[mi][ni][0] = (unsigned int)f2bf(s0) | ((unsigned int)f2bf(s1) << 16);
            gpk[mi][ni][1] = (unsigned int)f2bf(s2) | ((unsigned int)f2bf(s3) << 16);
        }
    }

    // ---- per-thread conv taps (c8 = 8 channels each), in registers ----
    const int c8g = tid & 31, rowg = tid >> 5;   // producer role
    float tp[8][8];
    #pragma unroll
    for (int cc2 = 0; cc2 < 8; ++cc2) {
        int c = m0 + c8g * 8 + cc2;
        float w10 = cw0[3*c], w11 = cw0[3*c+1], w12 = cw0[3*c+2];
        float w20 = cw1[3*c], w21 = cw1[3*c+1], w22 = cw1[3*c+2];
        float w40 = cw2[3*c], w41 = cw2[3*c+1], w42 = cw2[3*c+2];
        tp[cc2][0] = w40; tp[cc2][1] = w20; tp[cc2][2] = w10;
        tp[cc2][3] = w11 + w21 + w41;
        tp[cc2][4] = w12; tp[cc2][5] = w22; tp[cc2][6] = w42;
        tp[cc2][7] = cb0[c] + cb1[c] + cb2[c];
    }

    // ---- fused epilogue: two l-halves of 128 ----
    for (int lh = 0; lh < 2; ++lh) {
        const int gl0 = n0 + lh * 128 - 4;
        // stage xn [136 rows][256 c] (clamped rows; zeroed after)
        #pragma unroll
        for (int it = 0; it < 9; ++it) {
            int gi = tid + it * 512;
            if (gi < 136 * 32) {
                int row = gi >> 5, gr = gi & 31;
                int gl = gl0 + row;
                gl = gl < 0 ? 0 : (gl >= LL ? LL - 1 : gl);
                __builtin_amdgcn_global_load_lds(
                    (const __attribute__((address_space(1))) void*)(Bb + (size_t)gl * CC + m0 + gr * 8),
                    (__attribute__((address_space(3))) void*)(&sm.e.xnS[gi * 8]),
                    16, 0, 0);
            }
        }
        __syncthreads();
        if (nt == 0 && lh == 0 && tid < 128) {
            s16x8 z8 = {};
            *(s16x8*)&sm.e.xnS[((tid >> 5) * 32 + (tid & 31)) * 8] = z8;
        }
        if (nt == 7 && lh == 1 && tid < 128) {
            s16x8 z8 = {};
            *(s16x8*)&sm.e.xnS[((132 + (tid >> 5)) * 32 + (tid & 31)) * 8] = z8;
        }
        __syncthreads();
        // producers: conv -> qS (8 passes x 16 rows)
        #pragma unroll
        for (int p = 0; p < 8; ++p) {
            int lidx = p * 16 + rowg;
            s16x8 x0 = *(const s16x8*)&sm.e.xnS[(lidx)     * 256 + c8g * 8];
            s16x8 x2 = *(const s16x8*)&sm.e.xnS[(lidx + 2) * 256 + c8g * 8];
            s16x8 x3 = *(const s16x8*)&sm.e.xnS[(lidx + 3) * 256 + c8g * 8];
            s16x8 x4 = *(const s16x8*)&sm.e.xnS[(lidx + 4) * 256 + c8g * 8];
            s16x8 x5 = *(const s16x8*)&sm.e.xnS[(lidx + 5) * 256 + c8g * 8];
            s16x8 x6 = *(const s16x8*)&sm.e.xnS[(lidx + 6) * 256 + c8g * 8];
            s16x8 x8 = *(const s16x8*)&sm.e.xnS[(lidx + 8) * 256 + c8g * 8];
            float q[8];
            #pragma unroll
            for (int cc2 = 0; cc2 < 8; ++cc2) {
                q[cc2] = tp[cc2][0] * bf2f((unsigned short)x0[cc2])
                       + tp[cc2][1] * bf2f((unsigned short)x2[cc2])
                       + tp[cc2][2] * bf2f((unsigned short)x3[cc2])
                       + tp[cc2][3] * bf2f((unsigned short)x4[cc2])
                       + tp[cc2][4] * bf2f((unsigned short)x5[cc2])
                       + tp[cc2][5] * bf2f((unsigned short)x6[cc2])
                       + tp[cc2][6] * bf2f((unsigned short)x8[cc2])
                       + tp[cc2][7];
            }
            int s = lidx & 7;
            uint2 w0, w1;
            w0.x = (unsigned int)f2bf(q[0]) | ((unsigned int)f2bf(q[1]) << 16);
            w0.y = (unsigned int)f2bf(q[2]) | ((unsigned int)f2bf(q[3]) << 16);
            w1.x = (unsigned int)f2bf(q[4]) | ((unsigned int)f2bf(q[5]) << 16);
            w1.y = (unsigned int)f2bf(q[6]) | ((unsigned int)f2bf(q[7]) << 16);
            *(uint2*)&sm.e.qS[lidx * 256 + (((2 * c8g)     ^ s) * 4)] = w0;
            *(uint2*)&sm.e.qS[lidx * 256 + (((2 * c8g + 1) ^ s) * 4)] = w1;
        }
        __syncthreads();
        // consumers: waves whose l-range is in this half
        if ((wn >> 1) == lh) {
            #pragma unroll
            for (int ni = 0; ni < 4; ++ni) {
                int llocal = (wn & 1) * 64 + ni * 16 + lo;
                int s = llocal & 7;
                float sq = 0.f, dp = 0.f;
                #pragma unroll
                for (int mi = 0; mi < 8; ++mi) {
                    int gq = (wm * 32 + mi * 4 + hi) ^ s;
                    ushort4 qv = *(const ushort4*)&sm.e.qS[llocal * 256 + gq * 4];
                    unsigned short qa[4] = {qv.x, qv.y, qv.z, qv.w};
                    #pragma unroll
                    for (int r = 0; r < 4; ++r) {
                        int c = m0 + wm * 128 + mi * 16 + hi * 4 + r;
                        float g = bf2f((unsigned short)((r & 1) ? (gpk[mi][ni][r >> 1] >> 16)
                                                                : (gpk[mi][ni][r >> 1] & 0xffff)));
                        float p = bf2f(qa[r]) * g;
                        sq += p * p;
                        dp += p * (post_w[c] * lw[c]);
                    }
                }
                *(float2*)&sm.e.redS[(llocal * 8 + (wm * 4 + hi)) * 2] = make_float2(sq, dp);
            }
        }
        __syncthreads();
        if (tid < 128) {
            float sq = 0.f, dp = 0.f;
            #pragma unroll
            for (int j = 0; j < 8; ++j) {
                float2 v = *(const float2*)&sm.e.redS[(tid * 8 + j) * 2];
                sq += v.x; dp += v.y;
            }
            int l = n0 + lh * 128 + tid;
            *(float2*)&part[(((size_t)(b * 2 + mt)) * LL + l) * 2] = make_float2(sq, dp);
        }
        __syncthreads();
    }
}

// ------- K3b: combine 2 chunk-partials + adx -> out -------
__global__ __launch_bounds__(256) void k3b(
    const float* __restrict__ part, const float* __restrict__ adx,
    float* __restrict__ out) {
    int gl = blockIdx.x * 256 + threadIdx.x;   // B*L = 32768
    int b = gl >> 11, l = gl & 2047;
    float2 p0 = *(const float2*)&part[(((size_t)(b * 2 + 0)) * LL + l) * 2];
    float2 p1 = *(const float2*)&part[(((size_t)(b * 2 + 1)) * LL + l) * 2];
    float sq = p0.x + p1.x, dp = p0.y + p1.y;
    out[gl] = adx[gl] + rsqrtf(sq * (1.0f / CC) + 1e-5f) * dp;
}

extern "C" void kernel_launch(void* const* d_in, const int* in_sizes, int n_in,
                              void* d_out, int out_size, void* d_ws, size_t ws_size,
                              hipStream_t stream) {
    const float* x      = (const float*)d_in[1];
    const float* pre_w  = (const float*)d_in[2];
    const float* cw0    = (const float*)d_in[3];
    const float* cb0    = (const float*)d_in[4];
    const float* cw1    = (const float*)d_in[5];
    const float* cb1    = (const float*)d_in[6];
    const float* cw2    = (const float*)d_in[7];
    const float* cb2    = (const float*)d_in[8];
    const float* gw     = (const float*)d_in[9];
    const float* gb     = (const float*)d_in[10];
    const float* post_w = (const float*)d_in[11];
    const float* lw     = (const float*)d_in[12];
    float* out = (float*)d_out;

    // ws: gwb 0..0.5MB | xnt 0.5..34.1MB | adx +128KB | part +1MB
    char* ws = (char*)d_ws;
    unsigned short* gwb = (unsigned short*)(ws);
    unsigned short* xnt = (unsigned short*)(ws + 524288);
    float*          adx = (float*)(ws + 524288 + 33554432);
    float*          part = (float*)(ws + 524288 + 33554432 + 131072);

    hipLaunchKernelGGL(k0_cast,  dim3((CC * CC + 255) / 256), dim3(256), 0, stream, gw, gwb);
    hipLaunchKernelGGL(k1_rms_t, dim3(BB * (LL / 32)),        dim3(256), 0, stream,
                       x, pre_w, lw, xnt, adx);
    hipLaunchKernelGGL(k2_fused, dim3(LL / 256, CC / 256, BB), dim3(512), 0, stream,
                       gwb, xnt, gb, cw0, cb0, cw1, cb1, cw2, cb2, post_w, lw, part);
    hipLaunchKernelGGL(k3b,      dim3(BB * LL / 256),         dim3(256), 0, stream,
                       part, adx, out);
}

// Round 9
// 91.513 us; speedup vs baseline: 1.7259x; 1.7259x over previous
//
#include <hip/hip_runtime.h>
#include <hip/hip_bf16.h>

#define BB 16
#define CC 512
#define LL 2048

typedef float f32x4 __attribute__((ext_vector_type(4)));
typedef short s16x8 __attribute__((ext_vector_type(8)));

static __device__ __forceinline__ float bf2f(unsigned short u) {
    union { unsigned int i; float f; } v; v.i = ((unsigned int)u) << 16; return v.f;
}
static __device__ __forceinline__ unsigned short f2bf(float f) {
    union { float fv; unsigned int i; } v; v.fv = f;
    unsigned int x = v.i;
    return (unsigned short)((x + 0x7FFFu + ((x >> 16) & 1u)) >> 16);  // RNE
}

// ---------------- K0: cast gate_w f32 -> bf16 [512][512] ----------------
__global__ void k0_cast(const float* __restrict__ gw, unsigned short* __restrict__ gwb) {
    int i = blockIdx.x * 256 + threadIdx.x;
    if (i < CC * CC) gwb[i] = f2bf(gw[i]);
}

// ------- K1: RMS over C per (b,l); write x_norm^T bf16 [B][L][C] + adx = sum_c x*lw -------
#define K1_ST 520   // ushort stride (1040 B, 16B-aligned)
__global__ __launch_bounds__(256) void k1_rms_t(
    const float* __restrict__ x, const float* __restrict__ pre_w,
    const float* __restrict__ lw,
    unsigned short* __restrict__ xnt, float* __restrict__ adx) {
    __shared__ unsigned short tile[32 * K1_ST];   // [l][c] bf16, 33.3 KB
    __shared__ float red[32 * 33];
    __shared__ float red2[32 * 33];
    __shared__ float pwS[CC];
    __shared__ float lwS[CC];
    __shared__ float ivS[32];
    const int tid = threadIdx.x;
    const int b  = blockIdx.x >> 6;      // 64 l-tiles of 32
    const int lt = blockIdx.x & 63;
    const int l0 = lt * 32;
    const float* xb = x + (size_t)(b * CC) * LL + l0;

    for (int i = tid; i < CC; i += 256) { pwS[i] = pre_w[i]; lwS[i] = lw[i]; }
    __syncthreads();

    const int lq = tid & 7;      // l-quad: l = lq*4..+3
    const int cr = tid >> 3;     // 0..31
    f32x4 ssq = {0.f, 0.f, 0.f, 0.f};
    f32x4 sdx = {0.f, 0.f, 0.f, 0.f};
    #pragma unroll
    for (int p = 0; p < 16; ++p) {
        int c = p * 32 + cr;
        float lwc = lwS[c];
        f32x4 v = *(const f32x4*)(xb + (size_t)c * LL + lq * 4);
        #pragma unroll
        for (int r = 0; r < 4; ++r) {
            ssq[r] += v[r] * v[r];
            sdx[r] += v[r] * lwc;
            tile[(lq * 4 + r) * K1_ST + c] = f2bf(v[r]);
        }
    }
    #pragma unroll
    for (int r = 0; r < 4; ++r) {
        red[(lq * 4 + r) * 33 + cr]  = ssq[r];
        red2[(lq * 4 + r) * 33 + cr] = sdx[r];
    }
    __syncthreads();
    if (tid < 32) {
        float s = 0.f, sa = 0.f;
        #pragma unroll
        for (int g = 0; g < 32; ++g) { s += red[tid * 33 + g]; sa += red2[tid * 33 + g]; }
        ivS[tid] = rsqrtf(s * (1.0f / CC) + 1e-5f);
        adx[b * LL + l0 + tid] = sa;
    }
    __syncthreads();
    unsigned short* xo = xnt + ((size_t)b * LL + l0) * CC;
    #pragma unroll
    for (int p = 0; p < 8; ++p) {
        int g = p * 256 + tid;          // 2048 granules of 8 ushorts
        int l = g >> 6, c8 = (g & 63) * 8;
        s16x8 t = *(const s16x8*)&tile[l * K1_ST + c8];
        f32x4 w0 = *(const f32x4*)&pwS[c8];
        f32x4 w1 = *(const f32x4*)&pwS[c8 + 4];
        float iv = ivS[l];
        s16x8 o;
        #pragma unroll
        for (int r = 0; r < 4; ++r) {
            o[r]     = (short)f2bf(bf2f((unsigned short)t[r])     * iv * w0[r]);
            o[r + 4] = (short)f2bf(bf2f((unsigned short)t[r + 4]) * iv * w1[r]);
        }
        *(s16x8*)(xo + (size_t)l * CC + c8) = o;
    }
}

// ------- K2: per-batch GEMM + SiLU; output gate TRANSPOSED [B][L][C] bf16 -------
// GEMM core = R6 verbatim (256x256 tile, BK=32, 3-buf, counted vmcnt(8)).
// Epilogue: bias+SiLU -> LDS transpose tile [128 l][264 pad] -> coalesced stores.
__global__ __launch_bounds__(512, 2) void k2_gemm(
    const unsigned short* __restrict__ gwb,   // A [512][512] (d,c) row-major
    const unsigned short* __restrict__ xnt,   // B^T [B][2048][512] (l,c)
    const float* __restrict__ gate_b,
    unsigned short* __restrict__ gatet) {     // out bf16 [B][2048][512] (l,d)
    union Sm {
        struct { unsigned short A[3][256 * 32], B[3][256 * 32]; } g;   // 96 KB
        unsigned short T[128 * 264];                                    // 67.6 KB
    };
    __shared__ Sm sm;
    const int tid = threadIdx.x;
    const int w = tid >> 6, lane = tid & 63;
    const int lo = lane & 15, hi = lane >> 4;
    const int wm = w >> 2, wn = w & 3;           // 2M x 4N waves
    const int nt = blockIdx.x, mt = blockIdx.y, b = blockIdx.z;
    const int m0 = mt * 256, n0 = nt * 256;
    const unsigned short* Ab = gwb;
    const unsigned short* Bb = xnt + (size_t)b * LL * CC;

    #define STG(kt_, buf_)                                                            \
        {                                                                             \
            _Pragma("unroll")                                                         \
            for (int s_ = 0; s_ < 2; ++s_) {                                          \
                int g_ = tid + s_ * 512;                                              \
                int row_ = g_ >> 2, gin_ = g_ & 3;                                    \
                int ks_ = (kt_) * 32 + ((gin_ ^ ((row_ >> 1) & 3)) * 8);              \
                __builtin_amdgcn_global_load_lds(                                     \
                    (const __attribute__((address_space(1))) void*)(Ab + (size_t)(m0 + row_) * CC + ks_), \
                    (__attribute__((address_space(3))) void*)(&sm.g.A[buf_][g_ * 8]), \
                    16, 0, 0);                                                        \
                __builtin_amdgcn_global_load_lds(                                     \
                    (const __attribute__((address_space(1))) void*)(Bb + (size_t)(n0 + row_) * CC + ks_), \
                    (__attribute__((address_space(3))) void*)(&sm.g.B[buf_][g_ * 8]), \
                    16, 0, 0);                                                        \
            }                                                                         \
        }

    f32x4 acc[8][4] = {};
    const int fsw = (lo >> 1) & 3;

    STG(0, 0);
    STG(1, 1);
    #pragma unroll
    for (int kt = 0; kt < 16; ++kt) {
        const int buf = kt % 3;
        if (kt < 14) {
            STG(kt + 2, (kt + 2) % 3);
            asm volatile("s_waitcnt vmcnt(8)" ::: "memory");
        } else if (kt == 14) {
            asm volatile("s_waitcnt vmcnt(4)" ::: "memory");
        } else {
            asm volatile("s_waitcnt vmcnt(0)" ::: "memory");
        }
        __builtin_amdgcn_s_barrier();
        s16x8 af[8], bfr[4];
        #pragma unroll
        for (int mi = 0; mi < 8; ++mi)
            af[mi] = *(const s16x8*)&sm.g.A[buf][(wm * 128 + mi * 16 + lo) * 32 + ((hi ^ fsw) * 8)];
        #pragma unroll
        for (int ni = 0; ni < 4; ++ni)
            bfr[ni] = *(const s16x8*)&sm.g.B[buf][(wn * 64 + ni * 16 + lo) * 32 + ((hi ^ fsw) * 8)];
        __builtin_amdgcn_s_setprio(1);
        #pragma unroll
        for (int mi = 0; mi < 8; ++mi)
            #pragma unroll
            for (int ni = 0; ni < 4; ++ni)
                acc[mi][ni] = __builtin_amdgcn_mfma_f32_16x16x32_bf16(
                    af[mi], bfr[ni], acc[mi][ni], 0, 0, 0);
        __builtin_amdgcn_s_setprio(0);
        asm volatile("" ::: "memory");
        __builtin_amdgcn_s_barrier();
    }
    #undef STG

    // ---- epilogue: bias+SiLU -> T[l][d] (pad 264) -> coalesced [l][d] stores ----
    const int trow = tid >> 2, tq = tid & 3;
    for (int lh = 0; lh < 2; ++lh) {
        if ((wn >> 1) == lh) {
            #pragma unroll
            for (int mi = 0; mi < 8; ++mi) {
                f32x4 gb4 = *(const f32x4*)(gate_b + m0 + wm * 128 + mi * 16 + hi * 4);
                #pragma unroll
                for (int ni = 0; ni < 4; ++ni) {
                    int llocal = (wn & 1) * 64 + ni * 16 + lo;
                    f32x4 z = acc[mi][ni] + gb4;
                    ushort4 o;
                    o.x = f2bf(z[0] / (1.0f + __expf(-z[0])));
                    o.y = f2bf(z[1] / (1.0f + __expf(-z[1])));
                    o.z = f2bf(z[2] / (1.0f + __expf(-z[2])));
                    o.w = f2bf(z[3] / (1.0f + __expf(-z[3])));
                    *(ushort4*)&sm.T[llocal * 264 + wm * 128 + mi * 16 + hi * 4] = o;
                }
            }
        }
        __syncthreads();
        unsigned short* gout = gatet + ((size_t)b * LL + n0 + lh * 128 + trow) * CC + m0;
        #pragma unroll
        for (int j = 0; j < 8; ++j) {
            s16x8 v = *(const s16x8*)&sm.T[trow * 264 + tq * 8 + j * 32];
            *(s16x8*)(gout + tq * 8 + j * 32) = v;
        }
        __syncthreads();
    }
}

// ------- K3a: conv(7 taps from xnt) * gate_t -> post-RMS + logits -> out -------
// Block = full C x 32 l. grid (64, 16), 256 thr, 40KB LDS.
// Thread: 8 channels (c8 = tid&63) x 1 row per pass; full-wave shfl reduce.
__global__ __launch_bounds__(256) void k3a(
    const unsigned short* __restrict__ xnt,    // [B][L][C]
    const unsigned short* __restrict__ gatet,  // [B][L][C]
    const float* __restrict__ cw0, const float* __restrict__ cb0,
    const float* __restrict__ cw1, const float* __restrict__ cb1,
    const float* __restrict__ cw2, const float* __restrict__ cb2,
    const float* __restrict__ post_w, const float* __restrict__ lw,
    const float* __restrict__ adx, float* __restrict__ out) {
    __shared__ unsigned short xnS[40 * 512];   // rows l0-4 .. l0+35
    const int tid = threadIdx.x;
    const int lt = blockIdx.x, b = blockIdx.y;
    const int l0 = lt * 32;
    const unsigned short* Bb = xnt + (size_t)b * LL * CC;

    // stage 40 rows x 512 c (2560 granules of 16B), rows clamped at edges
    #pragma unroll
    for (int it = 0; it < 10; ++it) {
        int gi = tid + it * 256;
        int row = gi >> 6, gr = gi & 63;
        int gl = l0 - 4 + row;
        gl = gl < 0 ? 0 : (gl >= LL ? LL - 1 : gl);
        __builtin_amdgcn_global_load_lds(
            (const __attribute__((address_space(1))) void*)(Bb + (size_t)gl * CC + gr * 8),
            (__attribute__((address_space(3))) void*)(&xnS[gi * 8]),
            16, 0, 0);
    }
    __syncthreads();
    if (lt == 0) {          // zero halo rows 0..3 (granules 0..255)
        s16x8 z8 = {};
        *(s16x8*)&xnS[tid * 8] = z8;
    }
    if (lt == 63) {         // zero halo rows 36..39 (granules 2304..2559)
        s16x8 z8 = {};
        *(s16x8*)&xnS[(2304 + tid) * 8] = z8;
    }
    __syncthreads();

    const int c8 = tid & 63, wv = tid >> 6;
    // per-thread taps for channels c8*8 .. +7
    float tp[8][8], pwlw[8];
    #pragma unroll
    for (int cc2 = 0; cc2 < 8; ++cc2) {
        int c = c8 * 8 + cc2;
        float w10 = cw0[3*c], w11 = cw0[3*c+1], w12 = cw0[3*c+2];
        float w20 = cw1[3*c], w21 = cw1[3*c+1], w22 = cw1[3*c+2];
        float w40 = cw2[3*c], w41 = cw2[3*c+1], w42 = cw2[3*c+2];
        tp[cc2][0] = w40; tp[cc2][1] = w20; tp[cc2][2] = w10;
        tp[cc2][3] = w11 + w21 + w41;
        tp[cc2][4] = w12; tp[cc2][5] = w22; tp[cc2][6] = w42;
        tp[cc2][7] = cb0[c] + cb1[c] + cb2[c];
        pwlw[cc2] = post_w[c] * lw[c];
    }

    #pragma unroll
    for (int p = 0; p < 8; ++p) {
        const int lidx = p * 4 + wv;        // 0..31 (one row per wave per pass)
        s16x8 x0 = *(const s16x8*)&xnS[(lidx)     * 512 + c8 * 8];
        s16x8 x2 = *(const s16x8*)&xnS[(lidx + 2) * 512 + c8 * 8];
        s16x8 x3 = *(const s16x8*)&xnS[(lidx + 3) * 512 + c8 * 8];
        s16x8 x4 = *(const s16x8*)&xnS[(lidx + 4) * 512 + c8 * 8];
        s16x8 x5 = *(const s16x8*)&xnS[(lidx + 5) * 512 + c8 * 8];
        s16x8 x6 = *(const s16x8*)&xnS[(lidx + 6) * 512 + c8 * 8];
        s16x8 x8 = *(const s16x8*)&xnS[(lidx + 8) * 512 + c8 * 8];
        s16x8 gv = *(const s16x8*)&gatet[((size_t)b * LL + l0 + lidx) * CC + c8 * 8];
        float sq = 0.f, dp = 0.f;
        #pragma unroll
        for (int cc2 = 0; cc2 < 8; ++cc2) {
            float q = tp[cc2][0] * bf2f((unsigned short)x0[cc2])
                    + tp[cc2][1] * bf2f((unsigned short)x2[cc2])
                    + tp[cc2][2] * bf2f((unsigned short)x3[cc2])
                    + tp[cc2][3] * bf2f((unsigned short)x4[cc2])
                    + tp[cc2][4] * bf2f((unsigned short)x5[cc2])
                    + tp[cc2][5] * bf2f((unsigned short)x6[cc2])
                    + tp[cc2][6] * bf2f((unsigned short)x8[cc2])
                    + tp[cc2][7];
            float pv = q * bf2f((unsigned short)gv[cc2]);
            sq += pv * pv;
            dp += pv * pwlw[cc2];
        }
        #pragma unroll
        for (int m = 1; m < 64; m <<= 1) {
            sq += __shfl_xor(sq, m, 64);
            dp += __shfl_xor(dp, m, 64);
        }
        if ((tid & 63) == 0) {
            int l = l0 + lidx;
            out[(size_t)b * LL + l] = adx[b * LL + l]
                + rsqrtf(sq * (1.0f / CC) + 1e-5f) * dp;
        }
    }
}

extern "C" void kernel_launch(void* const* d_in, const int* in_sizes, int n_in,
                              void* d_out, int out_size, void* d_ws, size_t ws_size,
                              hipStream_t stream) {
    const float* x      = (const float*)d_in[1];
    const float* pre_w  = (const float*)d_in[2];
    const float* cw0    = (const float*)d_in[3];
    const float* cb0    = (const float*)d_in[4];
    const float* cw1    = (const float*)d_in[5];
    const float* cb1    = (const float*)d_in[6];
    const float* cw2    = (const float*)d_in[7];
    const float* cb2    = (const float*)d_in[8];
    const float* gw     = (const float*)d_in[9];
    const float* gb     = (const float*)d_in[10];
    const float* post_w = (const float*)d_in[11];
    const float* lw     = (const float*)d_in[12];
    float* out = (float*)d_out;

    // ws: gwb 0..0.5MB | xnt 0.5..34.1MB | adx +128KB | gate_t 33.5MB  (= 67.76MB, proven)
    char* ws = (char*)d_ws;
    unsigned short* gwb   = (unsigned short*)(ws);
    unsigned short* xnt   = (unsigned short*)(ws + 524288);
    float*          adx   = (float*)(ws + 524288 + 33554432);
    unsigned short* gatet = (unsigned short*)(ws + 524288 + 33554432 + 131072);

    hipLaunchKernelGGL(k0_cast,  dim3((CC * CC + 255) / 256), dim3(256), 0, stream, gw, gwb);
    hipLaunchKernelGGL(k1_rms_t, dim3(BB * (LL / 32)),        dim3(256), 0, stream,
                       x, pre_w, lw, xnt, adx);
    hipLaunchKernelGGL(k2_gemm,  dim3(LL / 256, CC / 256, BB), dim3(512), 0, stream,
                       gwb, xnt, gb, gatet);
    hipLaunchKernelGGL(k3a,      dim3(LL / 32, BB),           dim3(256), 0, stream,
                       xnt, gatet, cw0, cb0, cw1, cb1, cw2, cb2, post_w, lw, adx, out);
}